// Round 14
// baseline (291.981 us; speedup 1.0000x reference)
//
#include <hip/hip_runtime.h>

#define N 8192
#define D 512
#define KNEI 10
#define NC 8
#define GSPLIT 16
#define TRS 20
#define NTOT (GSPLIT * 2 * NC)  // 256 candidates per row

typedef __attribute__((ext_vector_type(8))) short bfv8;
typedef __attribute__((ext_vector_type(8))) unsigned short usv8;
typedef __attribute__((ext_vector_type(4))) float fv4;
typedef unsigned int uint32;

#define GLOAD_LDS16(gp, lp)                                                  \
  __builtin_amdgcn_global_load_lds(                                          \
      (const __attribute__((address_space(1))) void*)(gp),                   \
      (__attribute__((address_space(3))) void*)(lp), 16, 0, 0)

__device__ inline unsigned short f2bf(float f) {
  unsigned int u = __float_as_uint(f);
  return (unsigned short)((u + 0x7fffu + ((u >> 16) & 1u)) >> 16);
}

// ---------------------------------------------------------------------------
// Kernel 0: per-row fp32 sq (numpy-pairwise-style; validated rounds 3-7).
// ---------------------------------------------------------------------------
__global__ __launch_bounds__(256) void row_sq_np_kernel(const float* __restrict__ x,
                                                        float* __restrict__ sq) {
  const int wave = threadIdx.x >> 6;
  const int lane = threadIdx.x & 63;
  const int row = blockIdx.x * 4 + wave;
  const float* xr = x + (size_t)row * D;

  float s = 0.f;
  if (lane < 32) {
    const int leaf = lane >> 3;
    const int j = lane & 7;
    const float* a = xr + leaf * 128;
    float v = a[j];
    s = __fmul_rn(v, v);
#pragma unroll
    for (int i = 8; i < 128; i += 8) {
      v = a[i + j];
      s = __fadd_rn(s, __fmul_rn(v, v));
    }
  }
  float t1 = __shfl_xor(s, 1);
  s = __fadd_rn(s, t1);
  float t2 = __shfl_xor(s, 2);
  s = __fadd_rn(s, t2);
  float t4 = __shfl_xor(s, 4);
  s = __fadd_rn(s, t4);
  const float L0 = __shfl(s, 0);
  const float L1 = __shfl(s, 8);
  const float L2 = __shfl(s, 16);
  const float L3 = __shfl(s, 24);
  const float total = __fadd_rn(__fadd_rn(L0, L1), __fadd_rn(L2, L3));
  if (lane == 0) sq[row] = total;
}

// ---------------------------------------------------------------------------
// Kernel 0b: fp32 -> bf16 (RTNE).
// ---------------------------------------------------------------------------
__global__ __launch_bounds__(256) void cvt_bf16_kernel(const float* __restrict__ x,
                                                       unsigned short* __restrict__ xb) {
  const int base = (blockIdx.x * 256 + threadIdx.x) * 8;
  const float4 a = *(const float4*)(x + base);
  const float4 b = *(const float4*)(x + base + 4);
  usv8 o;
  o[0] = f2bf(a.x); o[1] = f2bf(a.y); o[2] = f2bf(a.z); o[3] = f2bf(a.w);
  o[4] = f2bf(b.x); o[5] = f2bf(b.y); o[6] = f2bf(b.z); o[7] = f2bf(b.w);
  *(usv8*)(xb + base) = o;
}

// ---------------------------------------------------------------------------
// Kernel 1: MFMA bf16 Gram + fused selection — SELECTION-UNDER-MFMA PIPELINE.
// r12 ablation: stage~39 / MFMA~32 / sel~38 us SERIALIZE (full = sum). The
// selection cost is exposed ds_read latency (proved by unroll-4's -10.7 us).
// Fix: 128x64 j-tiles (8 jt), acc[4][2]; Ct in a DEDICATED buffer; per kt of
// tile jt, a 4-candidate selection chunk of tile jt-1 runs between MFMA
// groups — VALU + LDS-read latency hide under the matrix pipe. Tail selects
// tile 7. Scan order (jt asc, cc asc) and accumulation order (kt,kh) are
// identical to the validated kernel -> ck bit-identical.
// LDS: As 16K + Bs 8K + Ct[64*129] 33K + sqj 2K = 59.6 KB -> 2 blocks/CU
// (occupancy proven non-binding r10/r11). Ct stride 129: selection reads
// 2-way (free), transpose writes <=4-way on 8 writes/thread/jt.
// ---------------------------------------------------------------------------
__global__ __launch_bounds__(256, 2) void knn_gemm_mfma(
    const unsigned short* __restrict__ xb, const float* __restrict__ sq,
    uint32* __restrict__ ck) {
  __shared__ __align__(16) unsigned short As[128 * 64];  // 16384 B
  __shared__ __align__(16) unsigned short Bs[64 * 64];   //  8192 B
  __shared__ __align__(16) float Ct[64 * 129];           // 33024 B
  __shared__ float sqj_all[512];                         //  2048 B

  const int tid = threadIdx.x;
  const int lane = tid & 63;
  const int wave = tid >> 6;
  const int wm = wave >> 1;   // wave row (64 i-rows each)
  const int wn = wave & 1;    // wave col (32 j-cols each)
  const int m = lane & 15;
  const int kg = lane >> 4;
  const int ibase = blockIdx.x * 128;
  const int jstart = blockIdx.y * (N / GSPLIT);

  const int srow = lane >> 3;
  const int schunk = lane & 7;
  const int sko = (schunk ^ srow) * 8;  // XOR-swizzled source k-offset

  sqj_all[tid] = sq[jstart + tid];
  sqj_all[256 + tid] = sq[jstart + 256 + tid];

  uint32 bk[NC];
#pragma unroll
  for (int t = 0; t < NC; ++t) bk[t] = 0xffffffffu;

  const int selrow = tid & 127;
  const int selhalf = tid >> 7;
  const int cbase = selhalf * 32;
  const float sqi_own = sq[ibase + selrow];

#pragma unroll 1
  for (int jt = 0; jt < 8; ++jt) {
    const int jbase = jstart + jt * 64;

    fv4 acc[4][2];
#pragma unroll
    for (int fi = 0; fi < 4; ++fi)
#pragma unroll
      for (int fj = 0; fj < 2; ++fj) acc[fi][fj] = (fv4)(0.f);

#pragma unroll 1
    for (int kt = 0; kt < 8; ++kt) {
      const int k0 = kt * 64;
      __syncthreads();  // prior kt's frag reads done; As/Bs reusable
#pragma unroll
      for (int q = 0; q < 4; ++q) {
        const int rbase = wave * 8 + q * 32;
        GLOAD_LDS16(xb + (size_t)(ibase + rbase + srow) * D + k0 + sko,
                    As + rbase * 64);
      }
#pragma unroll
      for (int q = 0; q < 2; ++q) {
        const int rbase = wave * 8 + q * 32;
        GLOAD_LDS16(xb + (size_t)(jbase + rbase + srow) * D + k0 + sko,
                    Bs + rbase * 64);
      }
      __syncthreads();  // staging visible

#pragma unroll
      for (int kh = 0; kh < 2; ++kh) {
        bfv8 af[4];
#pragma unroll
        for (int fi = 0; fi < 4; ++fi) {
          const int row = wm * 64 + fi * 16 + m;
          const int ch = (kh * 4 + kg) ^ (row & 7);
          af[fi] = *(const bfv8*)(As + row * 64 + ch * 8);
        }
#pragma unroll
        for (int fj = 0; fj < 2; ++fj) {
          const int row = wn * 32 + fj * 16 + m;
          const int ch = (kh * 4 + kg) ^ (row & 7);
          const bfv8 b = *(const bfv8*)(Bs + row * 64 + ch * 8);
#pragma unroll
          for (int fi = 0; fi < 4; ++fi) {
            acc[fi][fj] = __builtin_amdgcn_mfma_f32_16x16x32_bf16(
                af[fi], b, acc[fi][fj], 0, 0, 0);
          }
        }
      }

      // Interleaved selection: 4 candidates of tile jt-1 while the matrix
      // pipe crunches this kt's 16 MFMAs. Same global scan order as the
      // validated kernel (tile asc, cc asc) -> bk/ck bit-identical.
      if (jt > 0) {
        const int jb_prev = jbase - 64;
#pragma unroll
        for (int u = 0; u < 4; ++u) {
          const int cc = kt * 4 + u;
          const int c = cbase + cc;
          const float d = fmaxf(
              sqi_own - 2.f * Ct[c * 129 + selrow] + sqj_all[(jt - 1) * 64 + c],
              0.f);
          const uint32 key = ((uint32)f2bf(d) << 16) | (uint32)(jb_prev + c);
          if (key < bk[NC - 1]) {
            uint32 kv = key;
#pragma unroll
            for (int t = 0; t < NC; ++t) {
              if (kv < bk[t]) {
                const uint32 tmp = bk[t];
                bk[t] = kv;
                kv = tmp;
              }
            }
          }
        }
      }
    }
    __syncthreads();  // selection reads of Ct(jt-1) + frag reads done

    // Transpose acc -> Ct (C/D layout: col=lane&15, row=(lane>>4)*4+reg).
#pragma unroll
    for (int fi = 0; fi < 4; ++fi)
#pragma unroll
      for (int fj = 0; fj < 2; ++fj)
        *(fv4*)(&Ct[(wn * 32 + fj * 16 + m) * 129 + wm * 64 + fi * 16 + kg * 4]) =
            acc[fi][fj];
    __syncthreads();  // Ct(jt) visible for next jt's interleaved selection
  }

  // Tail: selection of tile 7 (same order as validated kernel).
  {
    const int jb7 = jstart + 7 * 64;
#pragma unroll 4
    for (int cc = 0; cc < 32; ++cc) {
      const int c = cbase + cc;
      const float d = fmaxf(
          sqi_own - 2.f * Ct[c * 129 + selrow] + sqj_all[7 * 64 + c], 0.f);
      const uint32 key = ((uint32)f2bf(d) << 16) | (uint32)(jb7 + c);
      if (key < bk[NC - 1]) {
        uint32 kv = key;
#pragma unroll
        for (int t = 0; t < NC; ++t) {
          if (kv < bk[t]) {
            const uint32 tmp = bk[t];
            bk[t] = kv;
            kv = tmp;
          }
        }
      }
    }
  }

  const size_t obase =
      ((size_t)(ibase + selrow) * (GSPLIT * 2) + blockIdx.y * 2 + selhalf) * NC;
#pragma unroll
  for (int t = 0; t < NC; ++t) ck[obase + t] = bk[t];
}

// ---------------------------------------------------------------------------
// Kernel 2: per-row merge — WAVE-PER-ROW (unchanged, validated).
// ---------------------------------------------------------------------------
__global__ __launch_bounds__(256) void merge_kernel(const float* __restrict__ x,
                                                    const float* __restrict__ sq,
                                                    const uint32* __restrict__ ck,
                                                    float* __restrict__ out) {
  __shared__ double zsh[4][TRS];
  __shared__ int jsh[4][TRS];
  __shared__ int jout[4][KNEI];

  const int wave = threadIdx.x >> 6;
  const int lane = threadIdx.x & 63;
  const int i = blockIdx.x * 4 + wave;

  const float4 xiA = *(const float4*)(x + (size_t)i * D + lane * 8);
  const float4 xiB = *(const float4*)(x + (size_t)i * D + lane * 8 + 4);
  const float sqi = sq[i];

  const uint32* ckr = ck + (size_t)i * NTOT + lane * 4;
  uint32 l0 = ckr[0], l1 = ckr[1], l2 = ckr[2], l3 = ckr[3];

  // (1) top-20 by packed key (bf16 score, then lower index — keys unique).
  int myselj = 0;
#pragma unroll 1
  for (int slot = 0; slot < TRS; ++slot) {
    uint32 r = min(min(l0, l1), min(l2, l3));
#pragma unroll
    for (int off = 32; off; off >>= 1) r = min(r, __shfl_xor(r, off));
    if (lane == slot) myselj = (int)(r & 0xffffu);
    if (l0 == r) l0 = 0xffffffffu;
    if (l1 == r) l1 = 0xffffffffu;
    if (l2 == r) l2 = 0xffffffffu;
    if (l3 == r) l3 = 0xffffffffu;
  }

  // (2) fp64 rescore with the reference's fp32 rounding chain (validated).
  double myz = 0.0;
#pragma unroll 2
  for (int c = 0; c < TRS; ++c) {
    const int j = __shfl(myselj, c);
    const float4 a = *(const float4*)(x + (size_t)j * D + lane * 8);
    const float4 b = *(const float4*)(x + (size_t)j * D + lane * 8 + 4);
    double s = (double)xiA.x * a.x + (double)xiA.y * a.y +
               (double)xiA.z * a.z + (double)xiA.w * a.w +
               (double)xiB.x * b.x + (double)xiB.y * b.y +
               (double)xiB.z * b.z + (double)xiB.w * b.w;
#pragma unroll
    for (int off = 32; off; off >>= 1) s += __shfl_xor(s, off);
    if (lane == c) {
      const float G = (float)s;
      const float y = __fsub_rn(sqi, __fmul_rn(2.0f, G));
      myz = (double)y + (double)sq[j];
    }
  }
  if (lane < TRS) {
    zsh[wave][lane] = myz;
    jsh[wave][lane] = myselj;
  }
  __syncthreads();

  // (3) serial top-10, eps tie-break — comparator identical to rounds 3-7.
  if (lane == 0) {
    unsigned int used = 0u;
    for (int slot = 0; slot < KNEI; ++slot) {
      int b = -1;
      double zb = 0.0;
      for (int c = 0; c < TRS; ++c) {
        if ((used >> c) & 1u) continue;
        const double zc = zsh[wave][c];
        if (b < 0) {
          b = c;
          zb = zc;
          continue;
        }
        const double eps = 1.25e-7 * fabs(zb);
        bool better;
        if (zc < zb - eps) better = true;
        else if (zc > zb + eps) better = false;
        else better = (jsh[wave][c] < jsh[wave][b]);
        if (better) {
          b = c;
          zb = zc;
        }
      }
      used |= (1u << b);
      jout[wave][slot] = jsh[wave][b];
    }
  }
  __syncthreads();

  // (4) smoothed = 0.5*x + 0.05 * sum(neighbors); 8 dims per lane.
  float4 sA = {0.f, 0.f, 0.f, 0.f}, sB = {0.f, 0.f, 0.f, 0.f};
#pragma unroll
  for (int mth = 0; mth < KNEI; ++mth) {
    const int j = jout[wave][mth];
    const float4 a = *(const float4*)(x + (size_t)j * D + lane * 8);
    const float4 b = *(const float4*)(x + (size_t)j * D + lane * 8 + 4);
    sA.x += a.x; sA.y += a.y; sA.z += a.z; sA.w += a.w;
    sB.x += b.x; sB.y += b.y; sB.z += b.z; sB.w += b.w;
  }
  float4 oA, oB;
  oA.x = 0.5f * xiA.x + 0.05f * sA.x;
  oA.y = 0.5f * xiA.y + 0.05f * sA.y;
  oA.z = 0.5f * xiA.z + 0.05f * sA.z;
  oA.w = 0.5f * xiA.w + 0.05f * sA.w;
  oB.x = 0.5f * xiB.x + 0.05f * sB.x;
  oB.y = 0.5f * xiB.y + 0.05f * sB.y;
  oB.z = 0.5f * xiB.z + 0.05f * sB.z;
  oB.w = 0.5f * xiB.w + 0.05f * sB.w;
  *(float4*)(out + (size_t)i * D + lane * 8) = oA;
  *(float4*)(out + (size_t)i * D + lane * 8 + 4) = oB;
}

// ---------------------------------------------------------------------------
extern "C" void kernel_launch(void* const* d_in, const int* in_sizes, int n_in,
                              void* d_out, int out_size, void* d_ws, size_t ws_size,
                              hipStream_t stream) {
  const float* x = (const float*)d_in[0];
  float* out = (float*)d_out;

  char* ws = (char*)d_ws;
  float* sq = (float*)ws;                              // 32 KB
  unsigned short* xb = (unsigned short*)(ws + 32768);  // 8 MB
  uint32* ck = (uint32*)(ws + 32768 + 8388608);        // 8 MB

  row_sq_np_kernel<<<N / 4, 256, 0, stream>>>(x, sq);
  cvt_bf16_kernel<<<(N * D) / (8 * 256), 256, 0, stream>>>(x, xb);
  knn_gemm_mfma<<<dim3(N / 128, GSPLIT), 256, 0, stream>>>(xb, sq, ck);
  merge_kernel<<<N / 4, 256, 0, stream>>>(x, sq, ck, out);
}

// Round 19
// 263.182 us; speedup vs baseline: 1.1094x; 1.1094x over previous
//
#include <hip/hip_runtime.h>

#define N 8192
#define D 512
#define KNEI 10
#define NC 8
#define GSPLIT 16
#define TRS 20
#define NTOT (GSPLIT * 2 * NC)  // 256 candidates per row

typedef __attribute__((ext_vector_type(8))) short bfv8;
typedef __attribute__((ext_vector_type(8))) unsigned short usv8;
typedef __attribute__((ext_vector_type(4))) float fv4;
typedef unsigned int uint32;

#define GLOAD_LDS16(gp, lp)                                                  \
  __builtin_amdgcn_global_load_lds(                                          \
      (const __attribute__((address_space(1))) void*)(gp),                   \
      (__attribute__((address_space(3))) void*)(lp), 16, 0, 0)

__device__ inline unsigned short f2bf(float f) {
  unsigned int u = __float_as_uint(f);
  return (unsigned short)((u + 0x7fffu + ((u >> 16) & 1u)) >> 16);
}

// ---------------------------------------------------------------------------
// Kernel 0: per-row fp32 sq (numpy-pairwise-style; validated rounds 3-7).
// ---------------------------------------------------------------------------
__global__ __launch_bounds__(256) void row_sq_np_kernel(const float* __restrict__ x,
                                                        float* __restrict__ sq) {
  const int wave = threadIdx.x >> 6;
  const int lane = threadIdx.x & 63;
  const int row = blockIdx.x * 4 + wave;
  const float* xr = x + (size_t)row * D;

  float s = 0.f;
  if (lane < 32) {
    const int leaf = lane >> 3;
    const int j = lane & 7;
    const float* a = xr + leaf * 128;
    float v = a[j];
    s = __fmul_rn(v, v);
#pragma unroll
    for (int i = 8; i < 128; i += 8) {
      v = a[i + j];
      s = __fadd_rn(s, __fmul_rn(v, v));
    }
  }
  float t1 = __shfl_xor(s, 1);
  s = __fadd_rn(s, t1);
  float t2 = __shfl_xor(s, 2);
  s = __fadd_rn(s, t2);
  float t4 = __shfl_xor(s, 4);
  s = __fadd_rn(s, t4);
  const float L0 = __shfl(s, 0);
  const float L1 = __shfl(s, 8);
  const float L2 = __shfl(s, 16);
  const float L3 = __shfl(s, 24);
  const float total = __fadd_rn(__fadd_rn(L0, L1), __fadd_rn(L2, L3));
  if (lane == 0) sq[row] = total;
}

// ---------------------------------------------------------------------------
// Kernel 0b: fp32 -> bf16 (RTNE).
// ---------------------------------------------------------------------------
__global__ __launch_bounds__(256) void cvt_bf16_kernel(const float* __restrict__ x,
                                                       unsigned short* __restrict__ xb) {
  const int base = (blockIdx.x * 256 + threadIdx.x) * 8;
  const float4 a = *(const float4*)(x + base);
  const float4 b = *(const float4*)(x + base + 4);
  usv8 o;
  o[0] = f2bf(a.x); o[1] = f2bf(a.y); o[2] = f2bf(a.z); o[3] = f2bf(a.w);
  o[4] = f2bf(b.x); o[5] = f2bf(b.y); o[6] = f2bf(b.z); o[7] = f2bf(b.w);
  *(usv8*)(xb + base) = o;
}

// ---------------------------------------------------------------------------
// Kernel 1 (PRODUCTION): r12 fat-tile (measured 133.7 us) with selection
// unroll 8 (4 gave -10.7 us vs 1; deeper batching of the independent
// Ct/sqj ds_reads). Scan order preserved -> ck bit-identical.
// r14's selection-under-MFMA REGRESSED (163.6): hosting it forced 64-col
// j-tiles, doubling kt-steps/barriers — fat-tile structure wins.
// ---------------------------------------------------------------------------
__global__ __launch_bounds__(256, 3) void knn_gemm_mfma(
    const unsigned short* __restrict__ xb, const float* __restrict__ sq,
    uint32* __restrict__ ck) {
  __shared__ __align__(16) float Ct[64 * 136];  // 34816 B
  __shared__ float sqj_all[512];                //  2048 B
  unsigned short* As = (unsigned short*)Ct;             // 128x64 bf16
  unsigned short* Bs = (unsigned short*)Ct + 128 * 64;  // 128x64 bf16

  const int tid = threadIdx.x;
  const int lane = tid & 63;
  const int wave = tid >> 6;
  const int wm = wave >> 1;
  const int wn = wave & 1;
  const int m = lane & 15;
  const int kg = lane >> 4;
  const int ibase = blockIdx.x * 128;
  const int jstart = blockIdx.y * (N / GSPLIT);

  const int srow = lane >> 3;
  const int schunk = lane & 7;
  const int sko = (schunk ^ srow) * 8;

  sqj_all[tid] = sq[jstart + tid];
  sqj_all[256 + tid] = sq[jstart + 256 + tid];

  uint32 bk[NC];
#pragma unroll
  for (int t = 0; t < NC; ++t) bk[t] = 0xffffffffu;

  const int selrow = tid & 127;
  const int selhalf = tid >> 7;
  const float sqi_own = sq[ibase + selrow];

#pragma unroll 1
  for (int jt = 0; jt < 4; ++jt) {
    const int jb128 = jstart + jt * 128;

    fv4 acc[4][4];
#pragma unroll
    for (int fi = 0; fi < 4; ++fi)
#pragma unroll
      for (int fj = 0; fj < 4; ++fj) acc[fi][fj] = (fv4)(0.f);

#pragma unroll 1
    for (int kt = 0; kt < 8; ++kt) {
      const int k0 = kt * 64;
      __syncthreads();
#pragma unroll
      for (int q = 0; q < 4; ++q) {
        const int rbase = wave * 8 + q * 32;
        GLOAD_LDS16(xb + (size_t)(ibase + rbase + srow) * D + k0 + sko,
                    As + rbase * 64);
      }
#pragma unroll
      for (int q = 0; q < 4; ++q) {
        const int rbase = wave * 8 + q * 32;
        GLOAD_LDS16(xb + (size_t)(jb128 + rbase + srow) * D + k0 + sko,
                    Bs + rbase * 64);
      }
      __syncthreads();

#pragma unroll
      for (int kh = 0; kh < 2; ++kh) {
        bfv8 af[4];
#pragma unroll
        for (int fi = 0; fi < 4; ++fi) {
          const int row = wm * 64 + fi * 16 + m;
          const int ch = (kh * 4 + kg) ^ (row & 7);
          af[fi] = *(const bfv8*)(As + row * 64 + ch * 8);
        }
#pragma unroll
        for (int fj = 0; fj < 4; ++fj) {
          const int row = wn * 64 + fj * 16 + m;
          const int ch = (kh * 4 + kg) ^ (row & 7);
          const bfv8 b = *(const bfv8*)(Bs + row * 64 + ch * 8);
#pragma unroll
          for (int fi = 0; fi < 4; ++fi) {
            acc[fi][fj] = __builtin_amdgcn_mfma_f32_16x16x32_bf16(
                af[fi], b, acc[fi][fj], 0, 0, 0);
          }
        }
      }
    }
    __syncthreads();

#pragma unroll 1
    for (int p = 0; p < 2; ++p) {
      if (wn == p) {
#pragma unroll
        for (int fi = 0; fi < 4; ++fi)
#pragma unroll
          for (int fj = 0; fj < 4; ++fj)
            *(fv4*)(&Ct[(fj * 16 + m) * 136 + wm * 64 + fi * 16 + kg * 4]) =
                acc[fi][fj];
      }
      __syncthreads();

      const int jbase = jb128 + p * 64;
      const int cbase = selhalf * 32;
#pragma unroll 8
      for (int cc = 0; cc < 32; ++cc) {
        const int c = cbase + cc;
        const float d = fmaxf(
            sqi_own - 2.f * Ct[c * 136 + selrow] + sqj_all[jt * 128 + p * 64 + c],
            0.f);
        const uint32 key = ((uint32)f2bf(d) << 16) | (uint32)(jbase + c);
        if (key < bk[NC - 1]) {
          uint32 kv = key;
#pragma unroll
          for (int t = 0; t < NC; ++t) {
            if (kv < bk[t]) {
              const uint32 tmp = bk[t];
              bk[t] = kv;
              kv = tmp;
            }
          }
        }
      }
      __syncthreads();
    }
  }

  const size_t obase =
      ((size_t)(ibase + selrow) * (GSPLIT * 2) + blockIdx.y * 2 + selhalf) * NC;
#pragma unroll
  for (int t = 0; t < NC; ++t) ck[obase + t] = bk[t];
}

// ---------------------------------------------------------------------------
// Kernel 2: per-row merge — WAVE-PER-ROW (unchanged, validated).
// ---------------------------------------------------------------------------
__global__ __launch_bounds__(256) void merge_kernel(const float* __restrict__ x,
                                                    const float* __restrict__ sq,
                                                    const uint32* __restrict__ ck,
                                                    float* __restrict__ out) {
  __shared__ double zsh[4][TRS];
  __shared__ int jsh[4][TRS];
  __shared__ int jout[4][KNEI];

  const int wave = threadIdx.x >> 6;
  const int lane = threadIdx.x & 63;
  const int i = blockIdx.x * 4 + wave;

  const float4 xiA = *(const float4*)(x + (size_t)i * D + lane * 8);
  const float4 xiB = *(const float4*)(x + (size_t)i * D + lane * 8 + 4);
  const float sqi = sq[i];

  const uint32* ckr = ck + (size_t)i * NTOT + lane * 4;
  uint32 l0 = ckr[0], l1 = ckr[1], l2 = ckr[2], l3 = ckr[3];

  // (1) top-20 by packed key (bf16 score, then lower index — keys unique).
  int myselj = 0;
#pragma unroll 1
  for (int slot = 0; slot < TRS; ++slot) {
    uint32 r = min(min(l0, l1), min(l2, l3));
#pragma unroll
    for (int off = 32; off; off >>= 1) r = min(r, __shfl_xor(r, off));
    if (lane == slot) myselj = (int)(r & 0xffffu);
    if (l0 == r) l0 = 0xffffffffu;
    if (l1 == r) l1 = 0xffffffffu;
    if (l2 == r) l2 = 0xffffffffu;
    if (l3 == r) l3 = 0xffffffffu;
  }

  // (2) fp64 rescore with the reference's fp32 rounding chain (validated).
  double myz = 0.0;
#pragma unroll 2
  for (int c = 0; c < TRS; ++c) {
    const int j = __shfl(myselj, c);
    const float4 a = *(const float4*)(x + (size_t)j * D + lane * 8);
    const float4 b = *(const float4*)(x + (size_t)j * D + lane * 8 + 4);
    double s = (double)xiA.x * a.x + (double)xiA.y * a.y +
               (double)xiA.z * a.z + (double)xiA.w * a.w +
               (double)xiB.x * b.x + (double)xiB.y * b.y +
               (double)xiB.z * b.z + (double)xiB.w * b.w;
#pragma unroll
    for (int off = 32; off; off >>= 1) s += __shfl_xor(s, off);
    if (lane == c) {
      const float G = (float)s;
      const float y = __fsub_rn(sqi, __fmul_rn(2.0f, G));
      myz = (double)y + (double)sq[j];
    }
  }
  if (lane < TRS) {
    zsh[wave][lane] = myz;
    jsh[wave][lane] = myselj;
  }
  __syncthreads();

  // (3) serial top-10, eps tie-break — comparator identical to rounds 3-7.
  if (lane == 0) {
    unsigned int used = 0u;
    for (int slot = 0; slot < KNEI; ++slot) {
      int b = -1;
      double zb = 0.0;
      for (int c = 0; c < TRS; ++c) {
        if ((used >> c) & 1u) continue;
        const double zc = zsh[wave][c];
        if (b < 0) {
          b = c;
          zb = zc;
          continue;
        }
        const double eps = 1.25e-7 * fabs(zb);
        bool better;
        if (zc < zb - eps) better = true;
        else if (zc > zb + eps) better = false;
        else better = (jsh[wave][c] < jsh[wave][b]);
        if (better) {
          b = c;
          zb = zc;
        }
      }
      used |= (1u << b);
      jout[wave][slot] = jsh[wave][b];
    }
  }
  __syncthreads();

  // (4) smoothed = 0.5*x + 0.05 * sum(neighbors); 8 dims per lane.
  float4 sA = {0.f, 0.f, 0.f, 0.f}, sB = {0.f, 0.f, 0.f, 0.f};
#pragma unroll
  for (int mth = 0; mth < KNEI; ++mth) {
    const int j = jout[wave][mth];
    const float4 a = *(const float4*)(x + (size_t)j * D + lane * 8);
    const float4 b = *(const float4*)(x + (size_t)j * D + lane * 8 + 4);
    sA.x += a.x; sA.y += a.y; sA.z += a.z; sA.w += a.w;
    sB.x += b.x; sB.y += b.y; sB.z += b.z; sB.w += b.w;
  }
  float4 oA, oB;
  oA.x = 0.5f * xiA.x + 0.05f * sA.x;
  oA.y = 0.5f * xiA.y + 0.05f * sA.y;
  oA.z = 0.5f * xiA.z + 0.05f * sA.z;
  oA.w = 0.5f * xiA.w + 0.05f * sA.w;
  oB.x = 0.5f * xiB.x + 0.05f * sB.x;
  oB.y = 0.5f * xiB.y + 0.05f * sB.y;
  oB.z = 0.5f * xiB.z + 0.05f * sB.z;
  oB.w = 0.5f * xiB.w + 0.05f * sB.w;
  *(float4*)(out + (size_t)i * D + lane * 8) = oA;
  *(float4*)(out + (size_t)i * D + lane * 8 + 4) = oB;
}

// ---------------------------------------------------------------------------
// MERGE PROBE (this round only): REP=2 clone of merge_kernel, flag-gated
// (full run once per process, ~3 us early-exit after). Quantifies merge's
// share of the stable ~122 us non-knn residual. Writes ONLY a checksum to
// the ck region (dead after merge; knn fully rewrites it next iteration).
// Neighbor indices masked to 8191 so rep-1's partially-clobbered ck keys
// cannot produce OOB reads. Appears in top-5 iff merge >= ~67 us.
// ---------------------------------------------------------------------------
__device__ int g_probe_done = 0;

__global__ void probe_flag_set() {
  __hip_atomic_store(&g_probe_done, 1, __ATOMIC_RELAXED,
                     __HIP_MEMORY_SCOPE_AGENT);
}

__global__ __launch_bounds__(256) void merge_probe(const float* __restrict__ x,
                                                   const float* __restrict__ sq,
                                                   uint32* __restrict__ ckd) {
  __shared__ int fdone;
  if (threadIdx.x == 0)
    fdone = __hip_atomic_load(&g_probe_done, __ATOMIC_RELAXED,
                              __HIP_MEMORY_SCOPE_AGENT);
  __syncthreads();
  if (fdone) return;

  __shared__ double zsh[4][TRS];
  __shared__ int jsh[4][TRS];
  __shared__ int jout[4][KNEI];

  const int wave = threadIdx.x >> 6;
  const int lane = threadIdx.x & 63;
  const int i = blockIdx.x * 4 + wave;

  const float4 xiA = *(const float4*)(x + (size_t)i * D + lane * 8);
  const float4 xiB = *(const float4*)(x + (size_t)i * D + lane * 8 + 4);
  const float sqi = sq[i];

  float csum = 0.f;

#pragma unroll 1
  for (int rep = 0; rep < 2; ++rep) {
    const uint32* ckr = ckd + (size_t)i * NTOT + lane * 4;
    uint32 l0 = ckr[0], l1 = ckr[1], l2 = ckr[2], l3 = ckr[3];

    int myselj = 0;
#pragma unroll 1
    for (int slot = 0; slot < TRS; ++slot) {
      uint32 r = min(min(l0, l1), min(l2, l3));
#pragma unroll
      for (int off = 32; off; off >>= 1) r = min(r, __shfl_xor(r, off));
      if (lane == slot) myselj = (int)(r & 0x1fffu);  // mask: in-bounds j
      if (l0 == r) l0 = 0xffffffffu;
      if (l1 == r) l1 = 0xffffffffu;
      if (l2 == r) l2 = 0xffffffffu;
      if (l3 == r) l3 = 0xffffffffu;
    }

    double myz = 0.0;
#pragma unroll 2
    for (int c = 0; c < TRS; ++c) {
      const int j = __shfl(myselj, c) & 8191;
      const float4 a = *(const float4*)(x + (size_t)j * D + lane * 8);
      const float4 b = *(const float4*)(x + (size_t)j * D + lane * 8 + 4);
      double s = (double)xiA.x * a.x + (double)xiA.y * a.y +
                 (double)xiA.z * a.z + (double)xiA.w * a.w +
                 (double)xiB.x * b.x + (double)xiB.y * b.y +
                 (double)xiB.z * b.z + (double)xiB.w * b.w;
#pragma unroll
      for (int off = 32; off; off >>= 1) s += __shfl_xor(s, off);
      if (lane == c) {
        const float G = (float)s;
        const float y = __fsub_rn(sqi, __fmul_rn(2.0f, G));
        myz = (double)y + (double)sq[j];
      }
    }
    if (lane < TRS) {
      zsh[wave][lane] = myz;
      jsh[wave][lane] = myselj & 8191;
    }
    __syncthreads();

    if (lane == 0) {
      unsigned int used = 0u;
      for (int slot = 0; slot < KNEI; ++slot) {
        int b = -1;
        double zb = 0.0;
        for (int c = 0; c < TRS; ++c) {
          if ((used >> c) & 1u) continue;
          const double zc = zsh[wave][c];
          if (b < 0) {
            b = c;
            zb = zc;
            continue;
          }
          const double eps = 1.25e-7 * fabs(zb);
          bool better;
          if (zc < zb - eps) better = true;
          else if (zc > zb + eps) better = false;
          else better = (jsh[wave][c] < jsh[wave][b]);
          if (better) {
            b = c;
            zb = zc;
          }
        }
        used |= (1u << b);
        jout[wave][slot] = jsh[wave][b];
      }
    }
    __syncthreads();

    float4 sA = {0.f, 0.f, 0.f, 0.f}, sB = {0.f, 0.f, 0.f, 0.f};
#pragma unroll
    for (int mth = 0; mth < KNEI; ++mth) {
      const int j = jout[wave][mth];
      const float4 a = *(const float4*)(x + (size_t)j * D + lane * 8);
      const float4 b = *(const float4*)(x + (size_t)j * D + lane * 8 + 4);
      sA.x += a.x; sA.y += a.y; sA.z += a.z; sA.w += a.w;
      sB.x += b.x; sB.y += b.y; sB.z += b.z; sB.w += b.w;
    }
    csum += 0.5f * xiA.x + 0.05f * sA.x + 0.5f * xiB.w + 0.05f * sB.w +
            sA.y + sA.z + sA.w + sB.x + sB.y + sB.z;
    __syncthreads();  // zsh/jsh/jout reusable next rep
  }

  // Signature write into dead ck region (i*64+lane < 524288 < 2M entries).
  ckd[(size_t)i * 64 + lane] = __float_as_uint(csum);
}

// ---------------------------------------------------------------------------
extern "C" void kernel_launch(void* const* d_in, const int* in_sizes, int n_in,
                              void* d_out, int out_size, void* d_ws, size_t ws_size,
                              hipStream_t stream) {
  const float* x = (const float*)d_in[0];
  float* out = (float*)d_out;

  char* ws = (char*)d_ws;
  float* sq = (float*)ws;                              // 32 KB
  unsigned short* xb = (unsigned short*)(ws + 32768);  // 8 MB
  uint32* ck = (uint32*)(ws + 32768 + 8388608);        // 8 MB

  row_sq_np_kernel<<<N / 4, 256, 0, stream>>>(x, sq);
  cvt_bf16_kernel<<<(N * D) / (8 * 256), 256, 0, stream>>>(x, xb);
  knn_gemm_mfma<<<dim3(N / 128, GSPLIT), 256, 0, stream>>>(xb, sq, ck);
  merge_kernel<<<N / 4, 256, 0, stream>>>(x, sq, ck, out);

  // Probe: runs after merge (ck dead until next iteration's knn rewrite).
  merge_probe<<<N / 4, 256, 0, stream>>>(x, sq, ck);
  probe_flag_set<<<1, 64, 0, stream>>>();
}